// Round 2
// baseline (240.460 us; speedup 1.0000x reference)
//
#include <hip/hip_runtime.h>
#include <hip/hip_bf16.h>
#include <math.h>

#define NCLS 20
#define KDIM 128
#define ALPHA 0.7f
#define BETA 1.5f

// ws layout (floats): [0, NCLS*KDIM) class sums; [NCLS*KDIM, +NCLS) counts;
//                     [NCLS*KDIM+NCLS, +NCLS) intra partial sums
#define WS_SUMS 0
#define WS_CNT (NCLS * KDIM)
#define WS_INTRA (NCLS * KDIM + NCLS)
#define WS_TOTAL (NCLS * KDIM + 2 * NCLS)

#define GRID 2048

__global__ void k_init(float* ws) {
    int i = blockIdx.x * blockDim.x + threadIdx.x;
    if (i < WS_TOTAL) ws[i] = 0.0f;
}

// Pass 1: per-class embedding sums + counts.
// 256 threads = 8 points/iter (32 lanes per point); lane s owns dims 4s..4s+3
// via one float4 load. unsafeAtomicAdd -> hw ds_add_f32 (no CAS loop, no
// return -> wave never stalls on the atomic).
__global__ void __launch_bounds__(256) k_sums(const float4* __restrict__ emb4,
                                              const int* __restrict__ t,
                                              float* __restrict__ ws, int N) {
    __shared__ float lsum[NCLS * KDIM];
    __shared__ float lcnt[NCLS];
    const int tid = threadIdx.x;
    for (int i = tid; i < NCLS * KDIM; i += 256) lsum[i] = 0.0f;
    if (tid < NCLS) lcnt[tid] = 0.0f;
    __syncthreads();

    const int s = tid & 31;
    const int pp = tid >> 5;
    const int stride = GRID * 8;
    for (int p = blockIdx.x * 8 + pp; p < N; p += 2 * stride) {
        const int p1 = p + stride;
        const int c0 = t[p];
        const float4 v0 = emb4[(size_t)p * 32 + s];
        int c1 = -1;
        float4 v1;
        if (p1 < N) {
            c1 = t[p1];
            v1 = emb4[(size_t)p1 * 32 + s];
        }
        float* b0 = lsum + c0 * KDIM + 4 * s;
        unsafeAtomicAdd(b0 + 0, v0.x);
        unsafeAtomicAdd(b0 + 1, v0.y);
        unsafeAtomicAdd(b0 + 2, v0.z);
        unsafeAtomicAdd(b0 + 3, v0.w);
        if (s == 0) unsafeAtomicAdd(&lcnt[c0], 1.0f);
        if (c1 >= 0) {
            float* b1 = lsum + c1 * KDIM + 4 * s;
            unsafeAtomicAdd(b1 + 0, v1.x);
            unsafeAtomicAdd(b1 + 1, v1.y);
            unsafeAtomicAdd(b1 + 2, v1.z);
            unsafeAtomicAdd(b1 + 3, v1.w);
            if (s == 0) unsafeAtomicAdd(&lcnt[c1], 1.0f);
        }
    }
    __syncthreads();
    for (int i = tid; i < NCLS * KDIM; i += 256) unsafeAtomicAdd(&ws[WS_SUMS + i], lsum[i]);
    if (tid < NCLS) unsafeAtomicAdd(&ws[WS_CNT + tid], lcnt[tid]);
}

// Pass 2: per-point distance to own-class mean, gated hinge^2, per-class sums.
__global__ void __launch_bounds__(256) k_intra(const float4* __restrict__ emb4,
                                               const int* __restrict__ t,
                                               const float* __restrict__ pts,
                                               float* __restrict__ ws, int N) {
    __shared__ float lmean[NCLS * KDIM];
    __shared__ float lintra[NCLS];
    const int tid = threadIdx.x;
    for (int i = tid; i < NCLS * KDIM; i += 256) {
        float cnt = ws[WS_CNT + i / KDIM];
        lmean[i] = ws[WS_SUMS + i] / fmaxf(cnt, 1.0f);
    }
    if (tid < NCLS) lintra[tid] = 0.0f;
    __syncthreads();

    const int s = tid & 31;
    const int pp = tid >> 5;
    const int stride = GRID * 8;
    for (int p = blockIdx.x * 8 + pp; p < N; p += 2 * stride) {
        const int p1 = p + stride;
        // ---- point p ----
        {
            const int c = t[p];
            const float4 v = emb4[(size_t)p * 32 + s];
            const float4 m = *(const float4*)&lmean[c * KDIM + 4 * s];
            float dx = v.x - m.x, dy = v.y - m.y, dz = v.z - m.z, dw = v.w - m.w;
            float d2 = dx * dx + dy * dy + dz * dz + dw * dw;
            for (int off = 16; off >= 1; off >>= 1) d2 += __shfl_down(d2, off, 32);
            if (s == 0) {
                float d = sqrtf(d2);
                float px = pts[(size_t)p * 3 + 0];
                float py = pts[(size_t)p * 3 + 1];
                float pz = pts[(size_t)p * 3 + 2];
                float r = sqrtf(px * px + py * py + pz * pz);
                float g = 1.0f / (1.0f + expf(-r));
                float h = fmaxf(d - ALPHA, 0.0f);
                unsafeAtomicAdd(&lintra[c], g * h * h);
            }
        }
        // ---- point p + stride ----
        if (p1 < N) {
            const int c = t[p1];
            const float4 v = emb4[(size_t)p1 * 32 + s];
            const float4 m = *(const float4*)&lmean[c * KDIM + 4 * s];
            float dx = v.x - m.x, dy = v.y - m.y, dz = v.z - m.z, dw = v.w - m.w;
            float d2 = dx * dx + dy * dy + dz * dz + dw * dw;
            for (int off = 16; off >= 1; off >>= 1) d2 += __shfl_down(d2, off, 32);
            if (s == 0) {
                float d = sqrtf(d2);
                float px = pts[(size_t)p1 * 3 + 0];
                float py = pts[(size_t)p1 * 3 + 1];
                float pz = pts[(size_t)p1 * 3 + 2];
                float r = sqrtf(px * px + py * py + pz * pz);
                float g = 1.0f / (1.0f + expf(-r));
                float h = fmaxf(d - ALPHA, 0.0f);
                unsafeAtomicAdd(&lintra[c], g * h * h);
            }
        }
    }
    __syncthreads();
    if (tid < NCLS) unsafeAtomicAdd(&ws[WS_INTRA + tid], lintra[tid]);
}

// Final: intra (clusters 1..19) + inter over 19x19 pair matrix -> scalar.
__global__ void __launch_bounds__(256) k_final(const float* __restrict__ ws,
                                               float* __restrict__ out) {
    __shared__ float lmean[NCLS * KDIM];
    __shared__ float red[256];
    const int tid = threadIdx.x;
    for (int i = tid; i < NCLS * KDIM; i += 256) {
        float cnt = ws[WS_CNT + i / KDIM];
        lmean[i] = ws[WS_SUMS + i] / fmaxf(cnt, 1.0f);
    }
    __syncthreads();

    float acc = 0.0f;
    // ordered pairs (i,j), i,j in [1,19], i != j  (19*19 = 361 cells)
    for (int idx = tid; idx < 361; idx += 256) {
        int i = idx / 19 + 1;
        int j = idx % 19 + 1;
        if (i != j) {
            float sq = 0.0f;
            const float* mi = lmean + i * KDIM;
            const float* mj = lmean + j * KDIM;
            for (int k = 0; k < KDIM; k++) {
                float df = mi[k] - mj[k];
                sq += df * df;
            }
            float dist = sqrtf(sq);
            float h = fmaxf(BETA - dist, 0.0f);
            acc += h * h;
        }
    }
    red[tid] = acc;
    __syncthreads();
    for (int st = 128; st >= 1; st >>= 1) {
        if (tid < st) red[tid] += red[tid + st];
        __syncthreads();
    }
    if (tid == 0) {
        float intra = 0.0f;
        for (int c = 1; c < NCLS; c++) {
            intra += ws[WS_INTRA + c] / fmaxf(ws[WS_CNT + c], 1.0f);
        }
        out[0] = intra / (float)NCLS + red[0] / (float)(NCLS * (NCLS - 1));
    }
}

extern "C" void kernel_launch(void* const* d_in, const int* in_sizes, int n_in,
                              void* d_out, int out_size, void* d_ws, size_t ws_size,
                              hipStream_t stream) {
    const float* pts = (const float*)d_in[0];
    const int* t = (const int*)d_in[1];
    const float4* emb4 = (const float4*)d_in[2];
    float* out = (float*)d_out;
    float* ws = (float*)d_ws;
    const int N = in_sizes[1];

    k_init<<<(WS_TOTAL + 255) / 256, 256, 0, stream>>>(ws);
    k_sums<<<GRID, 256, 0, stream>>>(emb4, t, ws, N);
    k_intra<<<GRID, 256, 0, stream>>>(emb4, t, pts, ws, N);
    k_final<<<1, 256, 0, stream>>>(ws, out);
}

// Round 3
// 209.089 us; speedup vs baseline: 1.1500x; 1.1500x over previous
//
#include <hip/hip_runtime.h>
#include <hip/hip_bf16.h>
#include <math.h>

#define NCLS 20
#define KDIM 128
#define ALPHA 0.7f
#define BETA 1.5f

// ws layout (floats): [0, NCLS*KDIM) class sums; [NCLS*KDIM, +NCLS) counts;
//                     [NCLS*KDIM+NCLS, +NCLS) intra partial sums
#define WS_SUMS 0
#define WS_CNT (NCLS * KDIM)
#define WS_INTRA (NCLS * KDIM + NCLS)
#define WS_TOTAL (NCLS * KDIM + 2 * NCLS)

__global__ void k_init(float* ws) {
    int i = blockIdx.x * blockDim.x + threadIdx.x;
    if (i < WS_TOTAL) ws[i] = 0.0f;
}

// Pass 1: per-class embedding sums + counts.
// ONE POINT PER WAVE: lane l owns dims 2l,2l+1 (float2, 512B/wave coalesced).
// Class id is wave-uniform -> readfirstlane + scalar switch into 20 named
// float2 register accumulators. Zero LDS atomics in the hot loop; flush is
// 40 ds_add per wave at the end.
#define SUMS_WAVES 16
#define SUMS_GRID 512

__global__ void __launch_bounds__(1024) k_sums(const float2* __restrict__ emb2,
                                               const int* __restrict__ t,
                                               float* __restrict__ ws, int N) {
    __shared__ float lsum[NCLS * KDIM];
    __shared__ float lcnt[NCLS];
    const int tid = threadIdx.x;
    for (int i = tid; i < NCLS * KDIM; i += 1024) lsum[i] = 0.0f;
    if (tid < NCLS) lcnt[tid] = 0.0f;
    __syncthreads();

    const int lane = tid & 63;
    const int gw = blockIdx.x * SUMS_WAVES + (tid >> 6);  // global wave id
    const int wstride = SUMS_GRID * SUMS_WAVES;           // 8192 waves

    float2 acc0 = {0,0}, acc1 = {0,0}, acc2 = {0,0}, acc3 = {0,0}, acc4 = {0,0};
    float2 acc5 = {0,0}, acc6 = {0,0}, acc7 = {0,0}, acc8 = {0,0}, acc9 = {0,0};
    float2 acc10 = {0,0}, acc11 = {0,0}, acc12 = {0,0}, acc13 = {0,0}, acc14 = {0,0};
    float2 acc15 = {0,0}, acc16 = {0,0}, acc17 = {0,0}, acc18 = {0,0}, acc19 = {0,0};
    int cnt0 = 0, cnt1 = 0, cnt2 = 0, cnt3 = 0, cnt4 = 0, cnt5 = 0, cnt6 = 0;
    int cnt7 = 0, cnt8 = 0, cnt9 = 0, cnt10 = 0, cnt11 = 0, cnt12 = 0, cnt13 = 0;
    int cnt14 = 0, cnt15 = 0, cnt16 = 0, cnt17 = 0, cnt18 = 0, cnt19 = 0;

    for (int p = gw; p < N; p += wstride) {
        const int c = __builtin_amdgcn_readfirstlane(t[p]);
        const float2 v = emb2[(size_t)p * 64 + lane];
        switch (c) {
#define CASE_ACC(i) case i: acc##i.x += v.x; acc##i.y += v.y; cnt##i += 1; break;
            CASE_ACC(0) CASE_ACC(1) CASE_ACC(2) CASE_ACC(3) CASE_ACC(4)
            CASE_ACC(5) CASE_ACC(6) CASE_ACC(7) CASE_ACC(8) CASE_ACC(9)
            CASE_ACC(10) CASE_ACC(11) CASE_ACC(12) CASE_ACC(13) CASE_ACC(14)
            CASE_ACC(15) CASE_ACC(16) CASE_ACC(17) CASE_ACC(18) CASE_ACC(19)
#undef CASE_ACC
        }
    }

    // flush registers -> LDS (40 ds_add + 20 scalar-count adds per wave)
#define FLUSH(i)                                                            \
    unsafeAtomicAdd(&lsum[i * KDIM + 2 * lane], acc##i.x);                  \
    unsafeAtomicAdd(&lsum[i * KDIM + 2 * lane + 1], acc##i.y);              \
    if (lane == 0 && cnt##i) unsafeAtomicAdd(&lcnt[i], (float)cnt##i);
    FLUSH(0) FLUSH(1) FLUSH(2) FLUSH(3) FLUSH(4)
    FLUSH(5) FLUSH(6) FLUSH(7) FLUSH(8) FLUSH(9)
    FLUSH(10) FLUSH(11) FLUSH(12) FLUSH(13) FLUSH(14)
    FLUSH(15) FLUSH(16) FLUSH(17) FLUSH(18) FLUSH(19)
#undef FLUSH
    __syncthreads();

    // block -> global
    for (int i = tid; i < NCLS * KDIM; i += 1024) unsafeAtomicAdd(&ws[WS_SUMS + i], lsum[i]);
    if (tid < NCLS) unsafeAtomicAdd(&ws[WS_CNT + tid], lcnt[tid]);
}

// Pass 2: per-point distance to own-class mean, gated hinge^2, per-class sums.
// (unchanged from R2 to isolate the k_sums A/B)
#define GRID 2048
__global__ void __launch_bounds__(256) k_intra(const float4* __restrict__ emb4,
                                               const int* __restrict__ t,
                                               const float* __restrict__ pts,
                                               float* __restrict__ ws, int N) {
    __shared__ float lmean[NCLS * KDIM];
    __shared__ float lintra[NCLS];
    const int tid = threadIdx.x;
    for (int i = tid; i < NCLS * KDIM; i += 256) {
        float cnt = ws[WS_CNT + i / KDIM];
        lmean[i] = ws[WS_SUMS + i] / fmaxf(cnt, 1.0f);
    }
    if (tid < NCLS) lintra[tid] = 0.0f;
    __syncthreads();

    const int s = tid & 31;
    const int pp = tid >> 5;
    const int stride = GRID * 8;
    for (int p = blockIdx.x * 8 + pp; p < N; p += 2 * stride) {
        const int p1 = p + stride;
        {
            const int c = t[p];
            const float4 v = emb4[(size_t)p * 32 + s];
            const float4 m = *(const float4*)&lmean[c * KDIM + 4 * s];
            float dx = v.x - m.x, dy = v.y - m.y, dz = v.z - m.z, dw = v.w - m.w;
            float d2 = dx * dx + dy * dy + dz * dz + dw * dw;
            for (int off = 16; off >= 1; off >>= 1) d2 += __shfl_down(d2, off, 32);
            if (s == 0) {
                float d = sqrtf(d2);
                float px = pts[(size_t)p * 3 + 0];
                float py = pts[(size_t)p * 3 + 1];
                float pz = pts[(size_t)p * 3 + 2];
                float r = sqrtf(px * px + py * py + pz * pz);
                float g = 1.0f / (1.0f + expf(-r));
                float h = fmaxf(d - ALPHA, 0.0f);
                unsafeAtomicAdd(&lintra[c], g * h * h);
            }
        }
        if (p1 < N) {
            const int c = t[p1];
            const float4 v = emb4[(size_t)p1 * 32 + s];
            const float4 m = *(const float4*)&lmean[c * KDIM + 4 * s];
            float dx = v.x - m.x, dy = v.y - m.y, dz = v.z - m.z, dw = v.w - m.w;
            float d2 = dx * dx + dy * dy + dz * dz + dw * dw;
            for (int off = 16; off >= 1; off >>= 1) d2 += __shfl_down(d2, off, 32);
            if (s == 0) {
                float d = sqrtf(d2);
                float px = pts[(size_t)p1 * 3 + 0];
                float py = pts[(size_t)p1 * 3 + 1];
                float pz = pts[(size_t)p1 * 3 + 2];
                float r = sqrtf(px * px + py * py + pz * pz);
                float g = 1.0f / (1.0f + expf(-r));
                float h = fmaxf(d - ALPHA, 0.0f);
                unsafeAtomicAdd(&lintra[c], g * h * h);
            }
        }
    }
    __syncthreads();
    if (tid < NCLS) unsafeAtomicAdd(&ws[WS_INTRA + tid], lintra[tid]);
}

// Final: intra (clusters 1..19) + inter over 19x19 pair matrix -> scalar.
__global__ void __launch_bounds__(256) k_final(const float* __restrict__ ws,
                                               float* __restrict__ out) {
    __shared__ float lmean[NCLS * KDIM];
    __shared__ float red[256];
    const int tid = threadIdx.x;
    for (int i = tid; i < NCLS * KDIM; i += 256) {
        float cnt = ws[WS_CNT + i / KDIM];
        lmean[i] = ws[WS_SUMS + i] / fmaxf(cnt, 1.0f);
    }
    __syncthreads();

    float acc = 0.0f;
    for (int idx = tid; idx < 361; idx += 256) {
        int i = idx / 19 + 1;
        int j = idx % 19 + 1;
        if (i != j) {
            float sq = 0.0f;
            const float* mi = lmean + i * KDIM;
            const float* mj = lmean + j * KDIM;
            for (int k = 0; k < KDIM; k++) {
                float df = mi[k] - mj[k];
                sq += df * df;
            }
            float dist = sqrtf(sq);
            float h = fmaxf(BETA - dist, 0.0f);
            acc += h * h;
        }
    }
    red[tid] = acc;
    __syncthreads();
    for (int st = 128; st >= 1; st >>= 1) {
        if (tid < st) red[tid] += red[tid + st];
        __syncthreads();
    }
    if (tid == 0) {
        float intra = 0.0f;
        for (int c = 1; c < NCLS; c++) {
            intra += ws[WS_INTRA + c] / fmaxf(ws[WS_CNT + c], 1.0f);
        }
        out[0] = intra / (float)NCLS + red[0] / (float)(NCLS * (NCLS - 1));
    }
}

extern "C" void kernel_launch(void* const* d_in, const int* in_sizes, int n_in,
                              void* d_out, int out_size, void* d_ws, size_t ws_size,
                              hipStream_t stream) {
    const float* pts = (const float*)d_in[0];
    const int* t = (const int*)d_in[1];
    const float2* emb2 = (const float2*)d_in[2];
    const float4* emb4 = (const float4*)d_in[2];
    float* out = (float*)d_out;
    float* ws = (float*)d_ws;
    const int N = in_sizes[1];

    k_init<<<(WS_TOTAL + 255) / 256, 256, 0, stream>>>(ws);
    k_sums<<<SUMS_GRID, 1024, 0, stream>>>(emb2, t, ws, N);
    k_intra<<<GRID, 256, 0, stream>>>(emb4, t, pts, ws, N);
    k_final<<<1, 256, 0, stream>>>(ws, out);
}

// Round 4
// 163.536 us; speedup vs baseline: 1.4704x; 1.2785x over previous
//
#include <hip/hip_runtime.h>
#include <hip/hip_bf16.h>
#include <math.h>

#define NCLS 20
#define KDIM 128
#define ALPHA 0.7f
#define BETA 1.5f

// ws layout (floats): [0, NCLS*KDIM) class sums; [NCLS*KDIM, +NCLS) counts;
//                     [NCLS*KDIM+NCLS, +NCLS) intra partial sums
#define WS_SUMS 0
#define WS_CNT (NCLS * KDIM)
#define WS_INTRA (NCLS * KDIM + NCLS)
#define WS_TOTAL (NCLS * KDIM + 2 * NCLS)

__global__ void k_init(float* ws) {
    int i = blockIdx.x * blockDim.x + threadIdx.x;
    if (i < WS_TOTAL) ws[i] = 0.0f;
}

// Pass 1: per-class embedding sums + counts.
// Exclusive-ownership structure: block = 128 threads = 2 waves, block owns a
// contiguous 128-point chunk. Wave w handles points 2i+w; lane k owns dims
// 2k,2k+1 of its wave's private LDS copy. Per point: one ds_read_b64 + 2 adds
// + one ds_write_b64 -- plain (non-atomic) RMW, race-free by construction.
// No atomics, no branches, no dynamic register indexing in the hot loop.
#define SUMS_BLK 128
#define SUMS_GRID 2048  // 2048 * 128 = 262144 points exactly

__global__ void __launch_bounds__(SUMS_BLK) k_sums(const float2* __restrict__ emb2,
                                                   const int* __restrict__ t,
                                                   float* __restrict__ ws, int N) {
    __shared__ float lsum[2][NCLS * KDIM];
    __shared__ int lcnt[2][NCLS];
    __shared__ int lds_t[SUMS_BLK];
    const int tid = threadIdx.x;
    const int w = tid >> 6;    // wave 0/1
    const int k = tid & 63;    // lane
    for (int i = tid; i < 2 * NCLS * KDIM; i += SUMS_BLK) (&lsum[0][0])[i] = 0.0f;
    if (tid < 2 * NCLS) (&lcnt[0][0])[tid] = 0;

    const int chunk = blockIdx.x * SUMS_BLK;
    if (chunk + tid < N) lds_t[tid] = t[chunk + tid];
    __syncthreads();

    float* myLsum = lsum[w];
    int* myLcnt = lcnt[w];
    const int npts = min(SUMS_BLK, N - chunk);

#pragma unroll 4
    for (int pl = w; pl < npts; pl += 2) {
        const int c = lds_t[pl];                       // LDS broadcast
        const float2 v = emb2[(size_t)(chunk + pl) * 64 + k];
        float* a = &myLsum[c * KDIM + 2 * k];
        a[0] += v.x;                                   // exclusive: (wave, lane)
        a[1] += v.y;                                   //   owns these 2 slots
        if (k == 0) myLcnt[c] += 1;
    }
    __syncthreads();

    // merge the two copies, flush to global
    for (int i = tid; i < NCLS * KDIM; i += SUMS_BLK)
        unsafeAtomicAdd(&ws[WS_SUMS + i], lsum[0][i] + lsum[1][i]);
    if (tid < NCLS)
        unsafeAtomicAdd(&ws[WS_CNT + tid], (float)(lcnt[0][tid] + lcnt[1][tid]));
}

// Pass 2: per-point distance to own-class mean, gated hinge^2, per-class sums.
// (unchanged -- proven ~30us)
#define GRID 2048
__global__ void __launch_bounds__(256) k_intra(const float4* __restrict__ emb4,
                                               const int* __restrict__ t,
                                               const float* __restrict__ pts,
                                               float* __restrict__ ws, int N) {
    __shared__ float lmean[NCLS * KDIM];
    __shared__ float lintra[NCLS];
    const int tid = threadIdx.x;
    for (int i = tid; i < NCLS * KDIM; i += 256) {
        float cnt = ws[WS_CNT + i / KDIM];
        lmean[i] = ws[WS_SUMS + i] / fmaxf(cnt, 1.0f);
    }
    if (tid < NCLS) lintra[tid] = 0.0f;
    __syncthreads();

    const int s = tid & 31;
    const int pp = tid >> 5;
    const int stride = GRID * 8;
    for (int p = blockIdx.x * 8 + pp; p < N; p += 2 * stride) {
        const int p1 = p + stride;
        {
            const int c = t[p];
            const float4 v = emb4[(size_t)p * 32 + s];
            const float4 m = *(const float4*)&lmean[c * KDIM + 4 * s];
            float dx = v.x - m.x, dy = v.y - m.y, dz = v.z - m.z, dw = v.w - m.w;
            float d2 = dx * dx + dy * dy + dz * dz + dw * dw;
            for (int off = 16; off >= 1; off >>= 1) d2 += __shfl_down(d2, off, 32);
            if (s == 0) {
                float d = sqrtf(d2);
                float px = pts[(size_t)p * 3 + 0];
                float py = pts[(size_t)p * 3 + 1];
                float pz = pts[(size_t)p * 3 + 2];
                float r = sqrtf(px * px + py * py + pz * pz);
                float g = 1.0f / (1.0f + expf(-r));
                float h = fmaxf(d - ALPHA, 0.0f);
                unsafeAtomicAdd(&lintra[c], g * h * h);
            }
        }
        if (p1 < N) {
            const int c = t[p1];
            const float4 v = emb4[(size_t)p1 * 32 + s];
            const float4 m = *(const float4*)&lmean[c * KDIM + 4 * s];
            float dx = v.x - m.x, dy = v.y - m.y, dz = v.z - m.z, dw = v.w - m.w;
            float d2 = dx * dx + dy * dy + dz * dz + dw * dw;
            for (int off = 16; off >= 1; off >>= 1) d2 += __shfl_down(d2, off, 32);
            if (s == 0) {
                float d = sqrtf(d2);
                float px = pts[(size_t)p1 * 3 + 0];
                float py = pts[(size_t)p1 * 3 + 1];
                float pz = pts[(size_t)p1 * 3 + 2];
                float r = sqrtf(px * px + py * py + pz * pz);
                float g = 1.0f / (1.0f + expf(-r));
                float h = fmaxf(d - ALPHA, 0.0f);
                unsafeAtomicAdd(&lintra[c], g * h * h);
            }
        }
    }
    __syncthreads();
    if (tid < NCLS) unsafeAtomicAdd(&ws[WS_INTRA + tid], lintra[tid]);
}

// Final: intra (clusters 1..19) + inter over 19x19 pair matrix -> scalar.
__global__ void __launch_bounds__(256) k_final(const float* __restrict__ ws,
                                               float* __restrict__ out) {
    __shared__ float lmean[NCLS * KDIM];
    __shared__ float red[256];
    const int tid = threadIdx.x;
    for (int i = tid; i < NCLS * KDIM; i += 256) {
        float cnt = ws[WS_CNT + i / KDIM];
        lmean[i] = ws[WS_SUMS + i] / fmaxf(cnt, 1.0f);
    }
    __syncthreads();

    float acc = 0.0f;
    for (int idx = tid; idx < 361; idx += 256) {
        int i = idx / 19 + 1;
        int j = idx % 19 + 1;
        if (i != j) {
            float sq = 0.0f;
            const float* mi = lmean + i * KDIM;
            const float* mj = lmean + j * KDIM;
            for (int k = 0; k < KDIM; k++) {
                float df = mi[k] - mj[k];
                sq += df * df;
            }
            float dist = sqrtf(sq);
            float h = fmaxf(BETA - dist, 0.0f);
            acc += h * h;
        }
    }
    red[tid] = acc;
    __syncthreads();
    for (int st = 128; st >= 1; st >>= 1) {
        if (tid < st) red[tid] += red[tid + st];
        __syncthreads();
    }
    if (tid == 0) {
        float intra = 0.0f;
        for (int c = 1; c < NCLS; c++) {
            intra += ws[WS_INTRA + c] / fmaxf(ws[WS_CNT + c], 1.0f);
        }
        out[0] = intra / (float)NCLS + red[0] / (float)(NCLS * (NCLS - 1));
    }
}

extern "C" void kernel_launch(void* const* d_in, const int* in_sizes, int n_in,
                              void* d_out, int out_size, void* d_ws, size_t ws_size,
                              hipStream_t stream) {
    const float* pts = (const float*)d_in[0];
    const int* t = (const int*)d_in[1];
    const float2* emb2 = (const float2*)d_in[2];
    const float4* emb4 = (const float4*)d_in[2];
    float* out = (float*)d_out;
    float* ws = (float*)d_ws;
    const int N = in_sizes[1];

    k_init<<<(WS_TOTAL + 255) / 256, 256, 0, stream>>>(ws);
    k_sums<<<SUMS_GRID, SUMS_BLK, 0, stream>>>(emb2, t, ws, N);
    k_intra<<<GRID, 256, 0, stream>>>(emb4, t, pts, ws, N);
    k_final<<<1, 256, 0, stream>>>(ws, out);
}